// Round 1
// baseline (105436.255 us; speedup 1.0000x reference)
//
#include <hip/hip_runtime.h>
#include <hip/hip_bf16.h>

#define B_   32
#define T_   512
#define NN_  16
#define CV_  150
#define D_   512
#define H_   512
#define BT_  16384      // B*T
#define K0_  1024       // 2*D
#define G3H_ 1536       // 3*H
#define NBLK_ 256       // gru persistent blocks (1 per CU)
#define JPB_  2         // hidden units per block

using bf16x8 = __attribute__((ext_vector_type(8))) short;
using f32x4  = __attribute__((ext_vector_type(4))) float;
using u32x4  = __attribute__((ext_vector_type(4))) unsigned int;

__device__ __forceinline__ unsigned short f2bf(float f){
  unsigned int u = __builtin_bit_cast(unsigned int, f);
  u += 0x7fffu + ((u >> 16) & 1u);           // RNE
  return (unsigned short)(u >> 16);
}

__device__ __forceinline__ void store8(unsigned short* p, f32x4 a, f32x4 b){
  union { unsigned short us[8]; u32x4 v; } u;
  u.us[0]=f2bf(a[0]); u.us[1]=f2bf(a[1]); u.us[2]=f2bf(a[2]); u.us[3]=f2bf(a[3]);
  u.us[4]=f2bf(b[0]); u.us[5]=f2bf(b[1]); u.us[6]=f2bf(b[2]); u.us[7]=f2bf(b[3]);
  *(u32x4*)p = u.v;
}

// ---------------- fp32 -> bf16 weight conversion ----------------
__global__ void convert_bf16(const float* __restrict__ src,
                             unsigned short* __restrict__ dst, int n){
  int i = blockIdx.x * 256 + threadIdx.x;
  if (i < n) dst[i] = f2bf(src[i]);
}

// ---------------- embeddings: chord row + masked mean of note rows ----------------
__global__ __launch_bounds__(64) void emb_kernel(
    const int* __restrict__ note, const int* __restrict__ chord,
    const float* __restrict__ ctab, const float* __restrict__ ntab,
    unsigned short* __restrict__ x0){
  const int bt = blockIdx.x;
  const int tid = threadIdx.x;
  __shared__ int sn[NN_];
  if (tid < NN_) sn[tid] = note[bt * NN_ + tid];
  __syncthreads();
  float alive = 1.f, cnt = 0.f;
  float msk[NN_];
  #pragma unroll
  for (int k = 0; k < NN_; ++k){ if (sn[k] == 0) alive = 0.f; msk[k] = alive; cnt += alive; }
  const float inv = 1.f / fmaxf(cnt, 1.f);
  const int ch = chord[bt];
  const int d0 = tid * 8;
  f32x4 c0 = {0.f,0.f,0.f,0.f}, c1 = {0.f,0.f,0.f,0.f};
  if (ch != 0){
    const float* cp = ctab + (size_t)ch * D_ + d0;
    c0 = *(const f32x4*)cp; c1 = *(const f32x4*)(cp + 4);
  }
  f32x4 s0 = {0.f,0.f,0.f,0.f}, s1 = {0.f,0.f,0.f,0.f};
  #pragma unroll
  for (int k = 0; k < NN_; ++k){
    if (msk[k] != 0.f){
      const float* np = ntab + (size_t)sn[k] * D_ + d0;
      s0 += *(const f32x4*)np;
      s1 += *(const f32x4*)(np + 4);
    }
  }
  s0 *= inv; s1 *= inv;
  unsigned short* o = x0 + (size_t)bt * K0_ + d0;
  store8(o, c0, c1);          // chord part [0..511]
  store8(o + D_, s0, s1);     // note part  [512..1023]
}

// ---------------- bf16 MFMA GEMM:  Y = X[M,K] @ W[N,K]^T + bias ----------------
// wmode 0: Y row-major [M][N] fp32
// wmode 1: Y in [T][N][B] layout (m = b*T + t), fp32  -- for xp consumed by gru
__global__ __launch_bounds__(256) void gemm_bt(
    const unsigned short* __restrict__ X, const unsigned short* __restrict__ W,
    const float* __restrict__ bias, float* __restrict__ Y,
    int M, int N, int K, int wmode){
  const int lane = threadIdx.x & 63;
  const int wave = threadIdx.x >> 6;
  const int l15 = lane & 15, kq4 = lane >> 4;
  const int m_frag = blockIdx.y * 64 + wave * 16 + l15;
  const int n_base = blockIdx.x * 64;
  f32x4 acc[4] = {{0.f,0.f,0.f,0.f},{0.f,0.f,0.f,0.f},{0.f,0.f,0.f,0.f},{0.f,0.f,0.f,0.f}};
  const unsigned short* xptr = X + (size_t)m_frag * K + kq4 * 8;
  const unsigned short* wptr[4];
  #pragma unroll
  for (int i = 0; i < 4; ++i){
    int n = n_base + i * 16 + l15;
    if (n >= N) n = N - 1;                     // clamp (stores guarded below)
    wptr[i] = W + (size_t)n * K + kq4 * 8;
  }
  for (int k0 = 0; k0 < K; k0 += 32){
    bf16x8 a = *(const bf16x8*)(xptr + k0);
    #pragma unroll
    for (int i = 0; i < 4; ++i){
      bf16x8 b = *(const bf16x8*)(wptr[i] + k0);
      acc[i] = __builtin_amdgcn_mfma_f32_16x16x32_bf16(a, b, acc[i], 0, 0, 0);
    }
  }
  // C/D: col = lane&15 (n), row = (lane>>4)*4 + reg (m)
  const int mrow = blockIdx.y * 64 + wave * 16 + kq4 * 4;
  #pragma unroll
  for (int i = 0; i < 4; ++i){
    int n = n_base + i * 16 + l15;
    if (n < N){
      float bv = bias[n];
      #pragma unroll
      for (int r = 0; r < 4; ++r){
        int m = mrow + r;
        float v = acc[i][r] + bv;
        if (wmode == 0) Y[(size_t)m * N + n] = v;
        else            Y[((size_t)(m & (T_-1)) * N + n) * B_ + (m >> 9)] = v;
      }
    }
  }
}

// ---------------- persistent GRU layer: 512 steps, flag barrier per step ----------------
// xp:   [T][3H][B] fp32 (x@Wih^T + bih, gate order r,z,n)
// whh:  [3H][H] fp32 (original input weights)
// hbuf: [2][H][B] fp32 double buffer (h transposed)
// xout: [B][T][H] bf16
__global__ __launch_bounds__(256) void gru_layer(
    const float* __restrict__ xp, const float* __restrict__ whh,
    const float* __restrict__ bhh, float* __restrict__ hbuf,
    unsigned short* __restrict__ xout, int* flags){
  __shared__ float w_s[6][512];     // rows: g*2+jl  (g=0:r,1:z,2:n)
  __shared__ float p_s[6][32][32];  // [row][kq][b]
  __shared__ float bh_s[6];
  const int tid = threadIdx.x;
  const int blk = blockIdx.x;
  const int j0 = blk * JPB_;

  for (int idx = tid; idx < 6 * 512; idx += 256){
    int r = idx >> 9, k = idx & 511;
    int g = r >> 1, jl = r & 1;
    w_s[r][k] = whh[(size_t)(g * H_ + j0 + jl) * H_ + k];
  }
  if (tid < 6){ int g = tid >> 1, jl = tid & 1; bh_s[tid] = bhh[g * H_ + j0 + jl]; }
  if (tid < JPB_ * B_){ int jl = tid >> 5, bb = tid & 31; hbuf[(size_t)(j0 + jl) * B_ + bb] = 0.f; }
  __threadfence();
  __syncthreads();
  if (tid == 0)
    __hip_atomic_store(&flags[blk], 1, __ATOMIC_RELEASE, __HIP_MEMORY_SCOPE_AGENT);
  if (tid < NBLK_){
    while (__hip_atomic_load(&flags[tid], __ATOMIC_ACQUIRE, __HIP_MEMORY_SCOPE_AGENT) < 1)
      __builtin_amdgcn_s_sleep(1);
  }
  __syncthreads();

  const int kq = tid >> 3;          // 0..31 (k split)
  const int b0 = (tid & 7) * 4;     // 0..28 (batch quad)

  for (int t = 0; t < T_; ++t){
    const float* hcur = hbuf + (size_t)(t & 1) * (H_ * B_);
    float*       hnxt = hbuf + (size_t)((t + 1) & 1) * (H_ * B_);
    f32x4 a0={0.f,0.f,0.f,0.f}, a1=a0, a2=a0, a3=a0, a4=a0, a5=a0;
    const float* hp0 = hcur + kq * B_ + b0;
    #pragma unroll
    for (int i = 0; i < 16; ++i){
      int k = kq + 32 * i;
      f32x4 hv = *(const f32x4*)(hp0 + i * (32 * B_));
      float w0 = w_s[0][k], w1 = w_s[1][k], w2 = w_s[2][k];
      float w3 = w_s[3][k], w4 = w_s[4][k], w5 = w_s[5][k];
      a0 += w0 * hv; a1 += w1 * hv; a2 += w2 * hv;
      a3 += w3 * hv; a4 += w4 * hv; a5 += w5 * hv;
    }
    *(f32x4*)&p_s[0][kq][b0] = a0;
    *(f32x4*)&p_s[1][kq][b0] = a1;
    *(f32x4*)&p_s[2][kq][b0] = a2;
    *(f32x4*)&p_s[3][kq][b0] = a3;
    *(f32x4*)&p_s[4][kq][b0] = a4;
    *(f32x4*)&p_s[5][kq][b0] = a5;
    __syncthreads();
    if (tid < JPB_ * B_){
      int jl = tid >> 5, bb = tid & 31;
      float sr = 0.f, sz = 0.f, sn = 0.f;
      #pragma unroll
      for (int q = 0; q < 32; ++q){
        sr += p_s[0 * JPB_ + jl][q][bb];
        sz += p_s[1 * JPB_ + jl][q][bb];
        sn += p_s[2 * JPB_ + jl][q][bb];
      }
      int j = j0 + jl;
      size_t xo = (size_t)t * G3H_ * B_ + bb;
      float xr = xp[xo + (size_t)(0 * H_ + j) * B_];
      float xz = xp[xo + (size_t)(1 * H_ + j) * B_];
      float xn = xp[xo + (size_t)(2 * H_ + j) * B_];
      sr += bh_s[0 * JPB_ + jl]; sz += bh_s[1 * JPB_ + jl]; sn += bh_s[2 * JPB_ + jl];
      float rg = 1.f / (1.f + __expf(-(xr + sr)));
      float zg = 1.f / (1.f + __expf(-(xz + sz)));
      float e  = __expf(2.f * (xn + rg * sn));
      float ng = (e - 1.f) / (e + 1.f);
      float hprev = hcur[(size_t)j * B_ + bb];
      float hnew = (1.f - zg) * ng + zg * hprev;
      hnxt[(size_t)j * B_ + bb] = hnew;
      xout[((size_t)bb * T_ + t) * H_ + j] = f2bf(hnew);
    }
    __threadfence();
    __syncthreads();
    if (tid == 0)
      __hip_atomic_store(&flags[blk], t + 2, __ATOMIC_RELEASE, __HIP_MEMORY_SCOPE_AGENT);
    if (tid < NBLK_){
      while (__hip_atomic_load(&flags[tid], __ATOMIC_ACQUIRE, __HIP_MEMORY_SCOPE_AGENT) < t + 2)
        __builtin_amdgcn_s_sleep(1);
    }
    __syncthreads();
  }
}

extern "C" void kernel_launch(void* const* d_in, const int* in_sizes, int n_in,
                              void* d_out, int out_size, void* d_ws, size_t ws_size,
                              hipStream_t stream){
  (void)in_sizes; (void)n_in; (void)out_size; (void)ws_size;
  const int*   note  = (const int*)d_in[0];
  const int*   chord = (const int*)d_in[1];
  const float* ctab  = (const float*)d_in[2];
  const float* ntab  = (const float*)d_in[3];
  const float* wih0  = (const float*)d_in[4];
  const float* whh0  = (const float*)d_in[5];
  const float* bih0  = (const float*)d_in[6];
  const float* bhh0  = (const float*)d_in[7];
  const float* wihr  = (const float*)d_in[8];
  const float* whhr  = (const float*)d_in[9];
  const float* bihr  = (const float*)d_in[10];
  const float* bhhr  = (const float*)d_in[11];
  const float* fcw   = (const float*)d_in[12];
  const float* fcb   = (const float*)d_in[13];
  float* out = (float*)d_out;

  char* ws = (char*)d_ws;
  size_t off = 0;
  auto alloc = [&](size_t bytes)->char*{
    char* p = ws + off; off = (off + bytes + 255) & ~(size_t)255; return p;
  };
  int*            flags  = (int*)alloc((size_t)5 * NBLK_ * sizeof(int));
  float*          xp     = (float*)alloc((size_t)BT_ * G3H_ * 4);
  unsigned short* x0     = (unsigned short*)alloc((size_t)BT_ * K0_ * 2);
  unsigned short* xA     = (unsigned short*)alloc((size_t)BT_ * H_ * 2);
  unsigned short* xB     = (unsigned short*)alloc((size_t)BT_ * H_ * 2);
  float*          hbuf   = (float*)alloc((size_t)2 * H_ * B_ * 4);
  unsigned short* wih0_b = (unsigned short*)alloc((size_t)G3H_ * K0_ * 2);
  unsigned short* wihr_b = (unsigned short*)alloc((size_t)4 * G3H_ * H_ * 2);
  unsigned short* fcw_b  = (unsigned short*)alloc((size_t)CV_ * H_ * 2);

  hipMemsetAsync(flags, 0, (size_t)5 * NBLK_ * sizeof(int), stream);

  { int n = G3H_ * K0_;    convert_bf16<<<(n + 255) / 256, 256, 0, stream>>>(wih0, wih0_b, n); }
  { int n = 4 * G3H_ * H_; convert_bf16<<<(n + 255) / 256, 256, 0, stream>>>(wihr, wihr_b, n); }
  { int n = CV_ * H_;      convert_bf16<<<(n + 255) / 256, 256, 0, stream>>>(fcw, fcw_b, n); }

  emb_kernel<<<BT_, 64, 0, stream>>>(note, chord, ctab, ntab, x0);

  // layer 0
  gemm_bt<<<dim3(G3H_ / 64, BT_ / 64), 256, 0, stream>>>(x0, wih0_b, bih0, xp, BT_, G3H_, K0_, 1);
  gru_layer<<<NBLK_, 256, 0, stream>>>(xp, whh0, bhh0, hbuf, xA, flags + 0 * NBLK_);

  unsigned short* xin = xA;
  unsigned short* xo  = xB;
  for (int l = 1; l < 5; ++l){
    gemm_bt<<<dim3(G3H_ / 64, BT_ / 64), 256, 0, stream>>>(
        xin, wihr_b + (size_t)(l - 1) * G3H_ * H_, bihr + (size_t)(l - 1) * G3H_,
        xp, BT_, G3H_, H_, 1);
    gru_layer<<<NBLK_, 256, 0, stream>>>(
        xp, whhr + (size_t)(l - 1) * G3H_ * H_, bhhr + (size_t)(l - 1) * G3H_,
        hbuf, xo, flags + l * NBLK_);
    unsigned short* tmp = xin; xin = xo; xo = tmp;
  }
  // FC: xin = layer-4 output
  gemm_bt<<<dim3((CV_ + 63) / 64, BT_ / 64), 256, 0, stream>>>(
      xin, fcw_b, fcb, out, BT_, CV_, H_, 0);
}

// Round 2
// 38978.970 us; speedup vs baseline: 2.7050x; 2.7050x over previous
//
#include <hip/hip_runtime.h>
#include <hip/hip_bf16.h>

#define B_   32
#define T_   512
#define NN_  16
#define CV_  150
#define D_   512
#define H_   512
#define BT_  16384      // B*T
#define K0_  1024       // 2*D
#define G3H_ 1536       // 3*H
#define NB_  128        // gru persistent blocks
#define J_   4          // hidden units per block (H_/NB_)

using bf16x8 = __attribute__((ext_vector_type(8))) short;
using f32x4  = __attribute__((ext_vector_type(4))) float;
using u32x4  = __attribute__((ext_vector_type(4))) unsigned int;

__device__ __forceinline__ unsigned short f2bf(float f){
  unsigned int u = __builtin_bit_cast(unsigned int, f);
  u += 0x7fffu + ((u >> 16) & 1u);           // RNE
  return (unsigned short)(u >> 16);
}

__device__ __forceinline__ void store8(unsigned short* p, f32x4 a, f32x4 b){
  union { unsigned short us[8]; u32x4 v; } u;
  u.us[0]=f2bf(a[0]); u.us[1]=f2bf(a[1]); u.us[2]=f2bf(a[2]); u.us[3]=f2bf(a[3]);
  u.us[4]=f2bf(b[0]); u.us[5]=f2bf(b[1]); u.us[6]=f2bf(b[2]); u.us[7]=f2bf(b[3]);
  *(u32x4*)p = u.v;
}

// ---------------- fp32 -> bf16 weight conversion ----------------
__global__ void convert_bf16(const float* __restrict__ src,
                             unsigned short* __restrict__ dst, int n){
  int i = blockIdx.x * 256 + threadIdx.x;
  if (i < n) dst[i] = f2bf(src[i]);
}

// ---------------- embeddings: chord row + masked mean of note rows ----------------
__global__ __launch_bounds__(64) void emb_kernel(
    const int* __restrict__ note, const int* __restrict__ chord,
    const float* __restrict__ ctab, const float* __restrict__ ntab,
    unsigned short* __restrict__ x0){
  const int bt = blockIdx.x;
  const int tid = threadIdx.x;
  __shared__ int sn[NN_];
  if (tid < NN_) sn[tid] = note[bt * NN_ + tid];
  __syncthreads();
  float alive = 1.f, cnt = 0.f;
  float msk[NN_];
  #pragma unroll
  for (int k = 0; k < NN_; ++k){ if (sn[k] == 0) alive = 0.f; msk[k] = alive; cnt += alive; }
  const float inv = 1.f / fmaxf(cnt, 1.f);
  const int ch = chord[bt];
  const int d0 = tid * 8;
  f32x4 c0 = {0.f,0.f,0.f,0.f}, c1 = {0.f,0.f,0.f,0.f};
  if (ch != 0){
    const float* cp = ctab + (size_t)ch * D_ + d0;
    c0 = *(const f32x4*)cp; c1 = *(const f32x4*)(cp + 4);
  }
  f32x4 s0 = {0.f,0.f,0.f,0.f}, s1 = {0.f,0.f,0.f,0.f};
  #pragma unroll
  for (int k = 0; k < NN_; ++k){
    if (msk[k] != 0.f){
      const float* np = ntab + (size_t)sn[k] * D_ + d0;
      s0 += *(const f32x4*)np;
      s1 += *(const f32x4*)(np + 4);
    }
  }
  s0 *= inv; s1 *= inv;
  unsigned short* o = x0 + (size_t)bt * K0_ + d0;
  store8(o, c0, c1);          // chord part [0..511]
  store8(o + D_, s0, s1);     // note part  [512..1023]
}

// ---------------- bf16 MFMA GEMM:  Y = X[M,K] @ W[N,K]^T + bias ----------------
// wmode 0: Y row-major [M][N] fp32
// wmode 1: Y in [T][N][B] layout (m = b*T + t), fp32  -- for xp consumed by gru
__global__ __launch_bounds__(256) void gemm_bt(
    const unsigned short* __restrict__ X, const unsigned short* __restrict__ W,
    const float* __restrict__ bias, float* __restrict__ Y,
    int M, int N, int K, int wmode){
  const int lane = threadIdx.x & 63;
  const int wave = threadIdx.x >> 6;
  const int l15 = lane & 15, kq4 = lane >> 4;
  const int m_frag = blockIdx.y * 64 + wave * 16 + l15;
  const int n_base = blockIdx.x * 64;
  f32x4 acc[4] = {{0.f,0.f,0.f,0.f},{0.f,0.f,0.f,0.f},{0.f,0.f,0.f,0.f},{0.f,0.f,0.f,0.f}};
  const unsigned short* xptr = X + (size_t)m_frag * K + kq4 * 8;
  const unsigned short* wptr[4];
  #pragma unroll
  for (int i = 0; i < 4; ++i){
    int n = n_base + i * 16 + l15;
    if (n >= N) n = N - 1;                     // clamp (stores guarded below)
    wptr[i] = W + (size_t)n * K + kq4 * 8;
  }
  for (int k0 = 0; k0 < K; k0 += 32){
    bf16x8 a = *(const bf16x8*)(xptr + k0);
    #pragma unroll
    for (int i = 0; i < 4; ++i){
      bf16x8 b = *(const bf16x8*)(wptr[i] + k0);
      acc[i] = __builtin_amdgcn_mfma_f32_16x16x32_bf16(a, b, acc[i], 0, 0, 0);
    }
  }
  // C/D: col = lane&15 (n), row = (lane>>4)*4 + reg (m)
  const int mrow = blockIdx.y * 64 + wave * 16 + kq4 * 4;
  #pragma unroll
  for (int i = 0; i < 4; ++i){
    int n = n_base + i * 16 + l15;
    if (n < N){
      float bv = bias[n];
      #pragma unroll
      for (int r = 0; r < 4; ++r){
        int m = mrow + r;
        float v = acc[i][r] + bv;
        if (wmode == 0) Y[(size_t)m * N + n] = v;
        else            Y[((size_t)(m & (T_-1)) * N + n) * B_ + (m >> 9)] = v;
      }
    }
  }
}

// ---------------- persistent GRU layer: 512 steps, central-counter barrier ----------------
// xp:   [T][3H][B] fp32 (x@Wih^T + bih, gate order r,z,n)
// whh:  [3H][H] fp32
// hbuf: [2][H][B] fp32 double buffer (h transposed, [k][b])
// xout: [B][T][H] bf16
// ctr:  one int per layer, pre-zeroed; monotonic arrival counter
__global__ __launch_bounds__(256) void gru_layer(
    const float* __restrict__ xp, const float* __restrict__ whh,
    const float* __restrict__ bhh, float* __restrict__ hbuf,
    unsigned short* __restrict__ xout, int* __restrict__ ctr){
  __shared__ float w_s[12][512];    // rows: g*4+jl (g=0:r,1:z,2:n)
  __shared__ float p_s[12][32][32]; // [row][kq][b]
  __shared__ float bh_s[12];
  const int tid = threadIdx.x;
  const int j0 = blockIdx.x * J_;

  for (int idx = tid; idx < 12 * 512; idx += 256){
    int r = idx >> 9, k = idx & 511;
    w_s[r][k] = whh[(size_t)((r >> 2) * H_ + j0 + (r & 3)) * H_ + k];
  }
  if (tid < 12) bh_s[tid] = bhh[(tid >> 2) * H_ + j0 + (tid & 3)];

  const int kq = tid >> 3;          // 0..31 (k split)
  const int b0 = (tid & 7) * 4;     // 0..28 (batch quad)
  const int jl = tid >> 5;          // 0..3  (for tid<128)
  const int bb = tid & 31;

  float hres = 0.f;                 // resident fp32 state for (j0+jl, bb)
  if (tid < J_ * B_) hbuf[(size_t)(j0 + jl) * B_ + bb] = 0.f;
  __syncthreads();
  if (tid == 0){
    __hip_atomic_fetch_add(ctr, 1, __ATOMIC_RELEASE, __HIP_MEMORY_SCOPE_AGENT);
    while (__hip_atomic_load(ctr, __ATOMIC_RELAXED, __HIP_MEMORY_SCOPE_AGENT) < NB_)
      __builtin_amdgcn_s_sleep(2);
  }
  __syncthreads();
  __builtin_amdgcn_fence(__ATOMIC_ACQUIRE, "agent");

  for (int t = 0; t < T_; ++t){
    const float* hc = hbuf + (size_t)(t & 1) * (H_ * B_);
    float*       hn = hbuf + (size_t)((t + 1) & 1) * (H_ * B_);
    f32x4 acc[12];
    #pragma unroll
    for (int r = 0; r < 12; ++r) acc[r] = {0.f,0.f,0.f,0.f};
    const float* hp = hc + kq * B_ + b0;
    #pragma unroll
    for (int i = 0; i < 16; ++i){
      f32x4 hv = *(const f32x4*)(hp + i * (32 * B_));
      const int k = kq + 32 * i;
      #pragma unroll
      for (int r = 0; r < 12; ++r) acc[r] += w_s[r][k] * hv;
    }
    #pragma unroll
    for (int r = 0; r < 12; ++r) *(f32x4*)&p_s[r][kq][b0] = acc[r];
    __syncthreads();
    if (tid < J_ * B_){
      float sr = bh_s[jl], sz = bh_s[4 + jl], sn = bh_s[8 + jl];
      #pragma unroll
      for (int q = 0; q < 32; ++q){
        sr += p_s[jl][q][bb];
        sz += p_s[4 + jl][q][bb];
        sn += p_s[8 + jl][q][bb];
      }
      const int j = j0 + jl;
      const size_t xo = (size_t)t * (G3H_ * B_) + bb;
      float xr = xp[xo + (size_t)(0 * H_ + j) * B_];
      float xz = xp[xo + (size_t)(1 * H_ + j) * B_];
      float xn = xp[xo + (size_t)(2 * H_ + j) * B_];
      float rg = 1.f / (1.f + __expf(-(xr + sr)));
      float zg = 1.f / (1.f + __expf(-(xz + sz)));
      float e  = __expf(2.f * (xn + rg * sn));
      float ng = (e - 1.f) / (e + 1.f);
      float hnew = (1.f - zg) * ng + zg * hres;
      hres = hnew;
      hn[(size_t)j * B_ + bb] = hnew;
      xout[((size_t)bb * T_ + t) * H_ + j] = f2bf(hnew);
    }
    __syncthreads();   // all p_s reads done, all global h stores issued (vmcnt drained)
    if (tid == 0){
      __hip_atomic_fetch_add(ctr, 1, __ATOMIC_RELEASE, __HIP_MEMORY_SCOPE_AGENT);
      const int target = NB_ * (t + 2);
      while (__hip_atomic_load(ctr, __ATOMIC_RELAXED, __HIP_MEMORY_SCOPE_AGENT) < target)
        __builtin_amdgcn_s_sleep(2);
    }
    __syncthreads();
    __builtin_amdgcn_fence(__ATOMIC_ACQUIRE, "agent");
  }
}

extern "C" void kernel_launch(void* const* d_in, const int* in_sizes, int n_in,
                              void* d_out, int out_size, void* d_ws, size_t ws_size,
                              hipStream_t stream){
  (void)in_sizes; (void)n_in; (void)out_size; (void)ws_size;
  const int*   note  = (const int*)d_in[0];
  const int*   chord = (const int*)d_in[1];
  const float* ctab  = (const float*)d_in[2];
  const float* ntab  = (const float*)d_in[3];
  const float* wih0  = (const float*)d_in[4];
  const float* whh0  = (const float*)d_in[5];
  const float* bih0  = (const float*)d_in[6];
  const float* bhh0  = (const float*)d_in[7];
  const float* wihr  = (const float*)d_in[8];
  const float* whhr  = (const float*)d_in[9];
  const float* bihr  = (const float*)d_in[10];
  const float* bhhr  = (const float*)d_in[11];
  const float* fcw   = (const float*)d_in[12];
  const float* fcb   = (const float*)d_in[13];
  float* out = (float*)d_out;

  char* ws = (char*)d_ws;
  size_t off = 0;
  auto alloc = [&](size_t bytes)->char*{
    char* p = ws + off; off = (off + bytes + 255) & ~(size_t)255; return p;
  };
  int*            ctrs   = (int*)alloc((size_t)5 * 64 * sizeof(int));  // 256B-strided slots
  float*          xp     = (float*)alloc((size_t)BT_ * G3H_ * 4);
  unsigned short* x0     = (unsigned short*)alloc((size_t)BT_ * K0_ * 2);
  unsigned short* xA     = (unsigned short*)alloc((size_t)BT_ * H_ * 2);
  unsigned short* xB     = (unsigned short*)alloc((size_t)BT_ * H_ * 2);
  float*          hbuf   = (float*)alloc((size_t)2 * H_ * B_ * 4);
  unsigned short* wih0_b = (unsigned short*)alloc((size_t)G3H_ * K0_ * 2);
  unsigned short* wihr_b = (unsigned short*)alloc((size_t)4 * G3H_ * H_ * 2);
  unsigned short* fcw_b  = (unsigned short*)alloc((size_t)CV_ * H_ * 2);

  hipMemsetAsync(ctrs, 0, (size_t)5 * 64 * sizeof(int), stream);

  { int n = G3H_ * K0_;    convert_bf16<<<(n + 255) / 256, 256, 0, stream>>>(wih0, wih0_b, n); }
  { int n = 4 * G3H_ * H_; convert_bf16<<<(n + 255) / 256, 256, 0, stream>>>(wihr, wihr_b, n); }
  { int n = CV_ * H_;      convert_bf16<<<(n + 255) / 256, 256, 0, stream>>>(fcw, fcw_b, n); }

  emb_kernel<<<BT_, 64, 0, stream>>>(note, chord, ctab, ntab, x0);

  // layer 0
  gemm_bt<<<dim3(G3H_ / 64, BT_ / 64), 256, 0, stream>>>(x0, wih0_b, bih0, xp, BT_, G3H_, K0_, 1);
  gru_layer<<<NB_, 256, 0, stream>>>(xp, whh0, bhh0, hbuf, xA, ctrs + 0 * 64);

  unsigned short* xin = xA;
  unsigned short* xo  = xB;
  for (int l = 1; l < 5; ++l){
    gemm_bt<<<dim3(G3H_ / 64, BT_ / 64), 256, 0, stream>>>(
        xin, wihr_b + (size_t)(l - 1) * G3H_ * H_, bihr + (size_t)(l - 1) * G3H_,
        xp, BT_, G3H_, H_, 1);
    gru_layer<<<NB_, 256, 0, stream>>>(
        xp, whhr + (size_t)(l - 1) * G3H_ * H_, bhhr + (size_t)(l - 1) * G3H_,
        hbuf, xo, ctrs + l * 64);
    unsigned short* tmp = xin; xin = xo; xo = tmp;
  }
  // FC: xin = layer-4 output
  gemm_bt<<<dim3((CV_ + 63) / 64, BT_ / 64), 256, 0, stream>>>(
      xin, fcw_b, fcb, out, BT_, CV_, H_, 0);
}

// Round 3
// 20944.820 us; speedup vs baseline: 5.0340x; 1.8610x over previous
//
#include <hip/hip_runtime.h>
#include <hip/hip_bf16.h>

#define B_   32
#define T_   512
#define NN_  16
#define CV_  150
#define D_   512
#define H_   512
#define BT_  16384      // B*T
#define K0_  1024       // 2*D
#define G3H_ 1536       // 3*H
#define NB_  128        // gru persistent blocks
#define J_   4          // hidden units per block (H_/NB_)

using bf16x8 = __attribute__((ext_vector_type(8))) short;
using f32x4  = __attribute__((ext_vector_type(4))) float;
using u32x4  = __attribute__((ext_vector_type(4))) unsigned int;
typedef unsigned long long u64;

__device__ __forceinline__ unsigned short f2bf(float f){
  unsigned int u = __builtin_bit_cast(unsigned int, f);
  u += 0x7fffu + ((u >> 16) & 1u);           // RNE
  return (unsigned short)(u >> 16);
}

__device__ __forceinline__ void store8(unsigned short* p, f32x4 a, f32x4 b){
  union { unsigned short us[8]; u32x4 v; } u;
  u.us[0]=f2bf(a[0]); u.us[1]=f2bf(a[1]); u.us[2]=f2bf(a[2]); u.us[3]=f2bf(a[3]);
  u.us[4]=f2bf(b[0]); u.us[5]=f2bf(b[1]); u.us[6]=f2bf(b[2]); u.us[7]=f2bf(b[3]);
  *(u32x4*)p = u.v;
}

// coherent (L3-level) helpers: relaxed agent-scope atomics -> sc1 ops, NO fences
__device__ __forceinline__ void st_coh_f32(float* p, float v){
  __hip_atomic_store((unsigned int*)p, __builtin_bit_cast(unsigned int, v),
                     __ATOMIC_RELAXED, __HIP_MEMORY_SCOPE_AGENT);
}
__device__ __forceinline__ u64 ld_coh_u64(const u64* p){
  return __hip_atomic_load(p, __ATOMIC_RELAXED, __HIP_MEMORY_SCOPE_AGENT);
}
__device__ __forceinline__ void st_flag(int* p, int v){
  __hip_atomic_store(p, v, __ATOMIC_RELAXED, __HIP_MEMORY_SCOPE_AGENT);
}
__device__ __forceinline__ int ld_flag(const int* p){
  return __hip_atomic_load(p, __ATOMIC_RELAXED, __HIP_MEMORY_SCOPE_AGENT);
}

// ---------------- fp32 -> bf16 weight conversion ----------------
__global__ void convert_bf16(const float* __restrict__ src,
                             unsigned short* __restrict__ dst, int n){
  int i = blockIdx.x * 256 + threadIdx.x;
  if (i < n) dst[i] = f2bf(src[i]);
}

// ---------------- embeddings: chord row + masked mean of note rows ----------------
__global__ __launch_bounds__(64) void emb_kernel(
    const int* __restrict__ note, const int* __restrict__ chord,
    const float* __restrict__ ctab, const float* __restrict__ ntab,
    unsigned short* __restrict__ x0){
  const int bt = blockIdx.x;
  const int tid = threadIdx.x;
  __shared__ int sn[NN_];
  if (tid < NN_) sn[tid] = note[bt * NN_ + tid];
  __syncthreads();
  float alive = 1.f, cnt = 0.f;
  float msk[NN_];
  #pragma unroll
  for (int k = 0; k < NN_; ++k){ if (sn[k] == 0) alive = 0.f; msk[k] = alive; cnt += alive; }
  const float inv = 1.f / fmaxf(cnt, 1.f);
  const int ch = chord[bt];
  const int d0 = tid * 8;
  f32x4 c0 = {0.f,0.f,0.f,0.f}, c1 = {0.f,0.f,0.f,0.f};
  if (ch != 0){
    const float* cp = ctab + (size_t)ch * D_ + d0;
    c0 = *(const f32x4*)cp; c1 = *(const f32x4*)(cp + 4);
  }
  f32x4 s0 = {0.f,0.f,0.f,0.f}, s1 = {0.f,0.f,0.f,0.f};
  #pragma unroll
  for (int k = 0; k < NN_; ++k){
    if (msk[k] != 0.f){
      const float* np = ntab + (size_t)sn[k] * D_ + d0;
      s0 += *(const f32x4*)np;
      s1 += *(const f32x4*)(np + 4);
    }
  }
  s0 *= inv; s1 *= inv;
  unsigned short* o = x0 + (size_t)bt * K0_ + d0;
  store8(o, c0, c1);          // chord part [0..511]
  store8(o + D_, s0, s1);     // note part  [512..1023]
}

// ---------------- bf16 MFMA GEMM:  Y = X[M,K] @ W[N,K]^T + bias ----------------
__global__ __launch_bounds__(256) void gemm_bt(
    const unsigned short* __restrict__ X, const unsigned short* __restrict__ W,
    const float* __restrict__ bias, float* __restrict__ Y,
    int M, int N, int K, int wmode){
  const int lane = threadIdx.x & 63;
  const int wave = threadIdx.x >> 6;
  const int l15 = lane & 15, kq4 = lane >> 4;
  const int m_frag = blockIdx.y * 64 + wave * 16 + l15;
  const int n_base = blockIdx.x * 64;
  f32x4 acc[4] = {{0.f,0.f,0.f,0.f},{0.f,0.f,0.f,0.f},{0.f,0.f,0.f,0.f},{0.f,0.f,0.f,0.f}};
  const unsigned short* xptr = X + (size_t)m_frag * K + kq4 * 8;
  const unsigned short* wptr[4];
  #pragma unroll
  for (int i = 0; i < 4; ++i){
    int n = n_base + i * 16 + l15;
    if (n >= N) n = N - 1;
    wptr[i] = W + (size_t)n * K + kq4 * 8;
  }
  for (int k0 = 0; k0 < K; k0 += 32){
    bf16x8 a = *(const bf16x8*)(xptr + k0);
    #pragma unroll
    for (int i = 0; i < 4; ++i){
      bf16x8 b = *(const bf16x8*)(wptr[i] + k0);
      acc[i] = __builtin_amdgcn_mfma_f32_16x16x32_bf16(a, b, acc[i], 0, 0, 0);
    }
  }
  const int mrow = blockIdx.y * 64 + wave * 16 + kq4 * 4;
  #pragma unroll
  for (int i = 0; i < 4; ++i){
    int n = n_base + i * 16 + l15;
    if (n < N){
      float bv = bias[n];
      #pragma unroll
      for (int r = 0; r < 4; ++r){
        int m = mrow + r;
        float v = acc[i][r] + bv;
        if (wmode == 0) Y[(size_t)m * N + n] = v;
        else            Y[((size_t)(m & (T_-1)) * N + n) * B_ + (m >> 9)] = v;
      }
    }
  }
}

// ---------------- persistent GRU layer: fence-free L3 barrier per step ----------------
// xp:    [T][3H][B] fp32
// whh:   [3H][H] fp32
// hbuf:  [2][H][B] fp32 double buffer (accessed ONLY via sc1 atomics)
// xout:  [B][T][H] bf16 (normal cached stores; flushed at kernel end)
// flags: NB_ ints, pre-zeroed; flags[blk] = number of completed phases (monotone)
__global__ __launch_bounds__(256) void gru_layer(
    const float* __restrict__ xp, const float* __restrict__ whh,
    const float* __restrict__ bhh, float* __restrict__ hbuf,
    unsigned short* __restrict__ xout, int* __restrict__ flags){
  __shared__ float w_s[12][512];    // rows: g*4+jl (g=0:r,1:z,2:n)
  __shared__ float p_s[12][32][32]; // [row][kq][b]
  __shared__ float bh_s[12];
  const int tid = threadIdx.x;
  const int blk = blockIdx.x;
  const int j0 = blk * J_;

  for (int idx = tid; idx < 12 * 512; idx += 256){
    int r = idx >> 9, k = idx & 511;
    w_s[r][k] = whh[(size_t)((r >> 2) * H_ + j0 + (r & 3)) * H_ + k];
  }
  if (tid < 12) bh_s[tid] = bhh[(tid >> 2) * H_ + j0 + (tid & 3)];

  const int kq = tid >> 3;          // 0..31 (k split)
  const int b0 = (tid & 7) * 4;     // 0..28 (batch quad)
  const int jl = tid >> 5;          // 0..3  (for tid<128)
  const int bb = tid & 31;
  const int j  = j0 + jl;

  float hres = 0.f;
  if (tid < J_ * B_) st_coh_f32(&hbuf[(size_t)j * B_ + bb], 0.f);
  __syncthreads();                  // drains vmcnt -> h0 stores at L3
  if (tid == 0) st_flag(&flags[blk], 1);
  if (tid < 64){
    while (true){
      int v0 = ld_flag(&flags[tid]);
      int v1 = ld_flag(&flags[tid + 64]);
      if (__all(v0 >= 1 && v1 >= 1)) break;
    }
  }
  __syncthreads();

  for (int t = 0; t < T_; ++t){
    const float* hc = hbuf + (size_t)(t & 1) * (H_ * B_);
    float*       hn = hbuf + (size_t)((t + 1) & 1) * (H_ * B_);

    // xp prefetch (independent of h; hides under matvec)
    float xr = 0.f, xz = 0.f, xn_ = 0.f;
    if (tid < J_ * B_){
      const size_t xo = (size_t)t * (G3H_ * B_) + bb;
      xr  = xp[xo + (size_t)(0 * H_ + j) * B_];
      xz  = xp[xo + (size_t)(1 * H_ + j) * B_];
      xn_ = xp[xo + (size_t)(2 * H_ + j) * B_];
    }

    f32x4 acc[12];
    #pragma unroll
    for (int r = 0; r < 12; ++r) acc[r] = {0.f,0.f,0.f,0.f};
    const u64* hp = (const u64*)(hc + kq * B_ + b0);   // 16B-aligned
    #pragma unroll
    for (int i = 0; i < 16; ++i){
      u64 lo = ld_coh_u64(hp + (size_t)i * 512);       // 32*B_ floats = 512 u64
      u64 hi = ld_coh_u64(hp + (size_t)i * 512 + 1);
      float2 f01 = __builtin_bit_cast(float2, lo);
      float2 f23 = __builtin_bit_cast(float2, hi);
      f32x4 hv = {f01.x, f01.y, f23.x, f23.y};
      const int k = kq + 32 * i;
      #pragma unroll
      for (int r = 0; r < 12; ++r) acc[r] += w_s[r][k] * hv;
    }
    #pragma unroll
    for (int r = 0; r < 12; ++r) *(f32x4*)&p_s[r][kq][b0] = acc[r];
    __syncthreads();

    if (tid < J_ * B_){
      float sr = bh_s[jl], sz = bh_s[4 + jl], sn = bh_s[8 + jl];
      #pragma unroll
      for (int q = 0; q < 32; ++q){
        sr += p_s[jl][q][bb];
        sz += p_s[4 + jl][q][bb];
        sn += p_s[8 + jl][q][bb];
      }
      float rg = 1.f / (1.f + __expf(-(xr + sr)));
      float zg = 1.f / (1.f + __expf(-(xz + sz)));
      float e  = __expf(2.f * (xn_ + rg * sn));
      float ng = (e - 1.f) / (e + 1.f);
      float hnew = (1.f - zg) * ng + zg * hres;
      hres = hnew;
      st_coh_f32(&hn[(size_t)j * B_ + bb], hnew);
      xout[((size_t)bb * T_ + t) * H_ + j] = f2bf(hnew);
    }
    __syncthreads();                // drains vmcnt -> h(t+1) stores at L3
    if (tid == 0) st_flag(&flags[blk], t + 2);
    if (tid < 64){
      const int target = t + 2;
      while (true){
        int v0 = ld_flag(&flags[tid]);
        int v1 = ld_flag(&flags[tid + 64]);
        if (__all(v0 >= target && v1 >= target)) break;
      }
    }
    __syncthreads();
  }
}

extern "C" void kernel_launch(void* const* d_in, const int* in_sizes, int n_in,
                              void* d_out, int out_size, void* d_ws, size_t ws_size,
                              hipStream_t stream){
  (void)in_sizes; (void)n_in; (void)out_size; (void)ws_size;
  const int*   note  = (const int*)d_in[0];
  const int*   chord = (const int*)d_in[1];
  const float* ctab  = (const float*)d_in[2];
  const float* ntab  = (const float*)d_in[3];
  const float* wih0  = (const float*)d_in[4];
  const float* whh0  = (const float*)d_in[5];
  const float* bih0  = (const float*)d_in[6];
  const float* bhh0  = (const float*)d_in[7];
  const float* wihr  = (const float*)d_in[8];
  const float* whhr  = (const float*)d_in[9];
  const float* bihr  = (const float*)d_in[10];
  const float* bhhr  = (const float*)d_in[11];
  const float* fcw   = (const float*)d_in[12];
  const float* fcb   = (const float*)d_in[13];
  float* out = (float*)d_out;

  char* ws = (char*)d_ws;
  size_t off = 0;
  auto alloc = [&](size_t bytes)->char*{
    char* p = ws + off; off = (off + bytes + 255) & ~(size_t)255; return p;
  };
  int*            flags  = (int*)alloc((size_t)5 * NB_ * sizeof(int));
  float*          xp     = (float*)alloc((size_t)BT_ * G3H_ * 4);
  unsigned short* x0     = (unsigned short*)alloc((size_t)BT_ * K0_ * 2);
  unsigned short* xA     = (unsigned short*)alloc((size_t)BT_ * H_ * 2);
  unsigned short* xB     = (unsigned short*)alloc((size_t)BT_ * H_ * 2);
  float*          hbuf   = (float*)alloc((size_t)2 * H_ * B_ * 4);
  unsigned short* wih0_b = (unsigned short*)alloc((size_t)G3H_ * K0_ * 2);
  unsigned short* wihr_b = (unsigned short*)alloc((size_t)4 * G3H_ * H_ * 2);
  unsigned short* fcw_b  = (unsigned short*)alloc((size_t)CV_ * H_ * 2);

  hipMemsetAsync(flags, 0, (size_t)5 * NB_ * sizeof(int), stream);

  { int n = G3H_ * K0_;    convert_bf16<<<(n + 255) / 256, 256, 0, stream>>>(wih0, wih0_b, n); }
  { int n = 4 * G3H_ * H_; convert_bf16<<<(n + 255) / 256, 256, 0, stream>>>(wihr, wihr_b, n); }
  { int n = CV_ * H_;      convert_bf16<<<(n + 255) / 256, 256, 0, stream>>>(fcw, fcw_b, n); }

  emb_kernel<<<BT_, 64, 0, stream>>>(note, chord, ctab, ntab, x0);

  // layer 0
  gemm_bt<<<dim3(G3H_ / 64, BT_ / 64), 256, 0, stream>>>(x0, wih0_b, bih0, xp, BT_, G3H_, K0_, 1);
  gru_layer<<<NB_, 256, 0, stream>>>(xp, whh0, bhh0, hbuf, xA, flags + 0 * NB_);

  unsigned short* xin = xA;
  unsigned short* xo  = xB;
  for (int l = 1; l < 5; ++l){
    gemm_bt<<<dim3(G3H_ / 64, BT_ / 64), 256, 0, stream>>>(
        xin, wihr_b + (size_t)(l - 1) * G3H_ * H_, bihr + (size_t)(l - 1) * G3H_,
        xp, BT_, G3H_, H_, 1);
    gru_layer<<<NB_, 256, 0, stream>>>(
        xp, whhr + (size_t)(l - 1) * G3H_ * H_, bhhr + (size_t)(l - 1) * G3H_,
        hbuf, xo, flags + l * NB_);
    unsigned short* tmp = xin; xin = xo; xo = tmp;
  }
  // FC: xin = layer-4 output
  gemm_bt<<<dim3((CV_ + 63) / 64, BT_ / 64), 256, 0, stream>>>(
      xin, fcw_b, fcb, out, BT_, CV_, H_, 0);
}

// Round 4
// 6382.327 us; speedup vs baseline: 16.5200x; 3.2817x over previous
//
#include <hip/hip_runtime.h>
#include <hip/hip_bf16.h>

#define B_   32
#define T_   512
#define NN_  16
#define CV_  150
#define D_   512
#define H_   512
#define BT_  16384      // B*T
#define K0_  1024       // 2*D
#define G3H_ 1536       // 3*H
#define SUBS_ 32        // blocks per layer in fused kernel
#define NBF_ 160        // 5 * SUBS_
#define WSZ_ 49152      // bf16 elems of swizzled W per block (96 frags * 512)

using bf16x8 = __attribute__((ext_vector_type(8))) short;
using f32x4  = __attribute__((ext_vector_type(4))) float;
using u32x4  = __attribute__((ext_vector_type(4))) unsigned int;
typedef unsigned long long u64;

__device__ __forceinline__ unsigned short f2bf(float f){
  unsigned int u = __builtin_bit_cast(unsigned int, f);
  u += 0x7fffu + ((u >> 16) & 1u);           // RNE
  return (unsigned short)(u >> 16);
}

__device__ __forceinline__ void store8(unsigned short* p, f32x4 a, f32x4 b){
  union { unsigned short us[8]; u32x4 v; } u;
  u.us[0]=f2bf(a[0]); u.us[1]=f2bf(a[1]); u.us[2]=f2bf(a[2]); u.us[3]=f2bf(a[3]);
  u.us[4]=f2bf(b[0]); u.us[5]=f2bf(b[1]); u.us[6]=f2bf(b[2]); u.us[7]=f2bf(b[3]);
  *(u32x4*)p = u.v;
}

// coherent (L3-level) helpers: relaxed agent-scope atomics -> sc1 ops, NO fences
__device__ __forceinline__ u64 ld_coh_u64(const u64* p){
  return __hip_atomic_load(p, __ATOMIC_RELAXED, __HIP_MEMORY_SCOPE_AGENT);
}
__device__ __forceinline__ void st_coh_u32(void* p, unsigned int v){
  __hip_atomic_store((unsigned int*)p, v, __ATOMIC_RELAXED, __HIP_MEMORY_SCOPE_AGENT);
}
__device__ __forceinline__ void st_flag(int* p, int v){
  __hip_atomic_store(p, v, __ATOMIC_RELAXED, __HIP_MEMORY_SCOPE_AGENT);
}
__device__ __forceinline__ int ld_flag(const int* p){
  return __hip_atomic_load(p, __ATOMIC_RELAXED, __HIP_MEMORY_SCOPE_AGENT);
}

// ---------------- fp32 -> bf16 weight conversion ----------------
__global__ void convert_bf16(const float* __restrict__ src,
                             unsigned short* __restrict__ dst, int n){
  int i = blockIdx.x * 256 + threadIdx.x;
  if (i < n) dst[i] = f2bf(src[i]);
}

// ---------------- swizzle W into MFMA A-frag layout ----------------
// wsw[blk=l*32+sub][fragl=g*32+ks][lam*8+e] ; ks<16 = Whh kstep, ks>=16 = Wih kstep
// row = g*512 + sub*16 + (lam&15); k = (ks&15)*32 + (lam>>4)*8 + e
__global__ void prep_wfrag(const float* __restrict__ whh0,
                           const float* __restrict__ whhr,
                           const float* __restrict__ wihr,
                           unsigned short* __restrict__ wsw, int total){
  int idx = blockIdx.x * 256 + threadIdx.x;
  if (idx >= total) return;
  int pos = idx & 511;
  int lam = pos >> 3, e = pos & 7;
  int fr  = idx >> 9;
  int ks  = fr & 31;
  int g   = (fr >> 5) % 3;
  int blk = fr / 96;
  int sub = blk & 31, l = blk >> 5;
  int row = g * 512 + sub * 16 + (lam & 15);
  int k   = (ks & 15) * 32 + (lam >> 4) * 8 + e;
  float v;
  if (l == 0) v = (ks < 16) ? whh0[(size_t)row * H_ + k] : 0.f;
  else {
    const float* w = (ks < 16) ? (whhr + (size_t)(l - 1) * G3H_ * H_)
                               : (wihr + (size_t)(l - 1) * G3H_ * H_);
    v = w[(size_t)row * H_ + k];
  }
  wsw[idx] = f2bf(v);
}

// bias_sw[blk][u][q]: q=0 r-bias, 1 z-bias, 2 xn-bias(bih_n), 3 hn-bias(bhh_n)
// l==0: xp already contains bih -> r/z use bhh only, q2 = 0
__global__ void prep_bias(const float* __restrict__ bhh0,
                          const float* __restrict__ bihr,
                          const float* __restrict__ bhhr,
                          float* __restrict__ bias_sw, int total){
  int idx = blockIdx.x * 256 + threadIdx.x;
  if (idx >= total) return;
  int q = idx & 3, u = (idx >> 2) & 15, sub = (idx >> 6) & 31, l = idx >> 11;
  int j = sub * 16 + u;
  float v;
  if (l == 0){
    v = (q == 0) ? bhh0[j] : (q == 1) ? bhh0[512 + j] : (q == 2) ? 0.f : bhh0[1024 + j];
  } else {
    const float* bi = bihr + (size_t)(l - 1) * G3H_;
    const float* bh = bhhr + (size_t)(l - 1) * G3H_;
    v = (q == 0) ? bi[j] + bh[j]
      : (q == 1) ? bi[512 + j] + bh[512 + j]
      : (q == 2) ? bi[1024 + j] : bh[1024 + j];
  }
  bias_sw[idx] = v;
}

// ---------------- embeddings ----------------
__global__ __launch_bounds__(64) void emb_kernel(
    const int* __restrict__ note, const int* __restrict__ chord,
    const float* __restrict__ ctab, const float* __restrict__ ntab,
    unsigned short* __restrict__ x0){
  const int bt = blockIdx.x;
  const int tid = threadIdx.x;
  __shared__ int sn[NN_];
  if (tid < NN_) sn[tid] = note[bt * NN_ + tid];
  __syncthreads();
  float alive = 1.f, cnt = 0.f;
  float msk[NN_];
  #pragma unroll
  for (int k = 0; k < NN_; ++k){ if (sn[k] == 0) alive = 0.f; msk[k] = alive; cnt += alive; }
  const float inv = 1.f / fmaxf(cnt, 1.f);
  const int ch = chord[bt];
  const int d0 = tid * 8;
  f32x4 c0 = {0.f,0.f,0.f,0.f}, c1 = {0.f,0.f,0.f,0.f};
  if (ch != 0){
    const float* cp = ctab + (size_t)ch * D_ + d0;
    c0 = *(const f32x4*)cp; c1 = *(const f32x4*)(cp + 4);
  }
  f32x4 s0 = {0.f,0.f,0.f,0.f}, s1 = {0.f,0.f,0.f,0.f};
  #pragma unroll
  for (int k = 0; k < NN_; ++k){
    if (msk[k] != 0.f){
      const float* np = ntab + (size_t)sn[k] * D_ + d0;
      s0 += *(const f32x4*)np;
      s1 += *(const f32x4*)(np + 4);
    }
  }
  s0 *= inv; s1 *= inv;
  unsigned short* o = x0 + (size_t)bt * K0_ + d0;
  store8(o, c0, c1);
  store8(o + D_, s0, s1);
}

// ---------------- bf16 MFMA GEMM:  Y = X[M,K] @ W[N,K]^T + bias ----------------
__global__ __launch_bounds__(256) void gemm_bt(
    const unsigned short* __restrict__ X, const unsigned short* __restrict__ W,
    const float* __restrict__ bias, float* __restrict__ Y,
    int M, int N, int K, int wmode){
  const int lane = threadIdx.x & 63;
  const int wave = threadIdx.x >> 6;
  const int l15 = lane & 15, kq4 = lane >> 4;
  const int m_frag = blockIdx.y * 64 + wave * 16 + l15;
  const int n_base = blockIdx.x * 64;
  f32x4 acc[4] = {{0.f,0.f,0.f,0.f},{0.f,0.f,0.f,0.f},{0.f,0.f,0.f,0.f},{0.f,0.f,0.f,0.f}};
  const unsigned short* xptr = X + (size_t)m_frag * K + kq4 * 8;
  const unsigned short* wptr[4];
  #pragma unroll
  for (int i = 0; i < 4; ++i){
    int n = n_base + i * 16 + l15;
    if (n >= N) n = N - 1;
    wptr[i] = W + (size_t)n * K + kq4 * 8;
  }
  for (int k0 = 0; k0 < K; k0 += 32){
    bf16x8 a = *(const bf16x8*)(xptr + k0);
    #pragma unroll
    for (int i = 0; i < 4; ++i){
      bf16x8 b = *(const bf16x8*)(wptr[i] + k0);
      acc[i] = __builtin_amdgcn_mfma_f32_16x16x32_bf16(a, b, acc[i], 0, 0, 0);
    }
  }
  const int mrow = blockIdx.y * 64 + wave * 16 + kq4 * 4;
  #pragma unroll
  for (int i = 0; i < 4; ++i){
    int n = n_base + i * 16 + l15;
    if (n < N){
      float bv = bias[n];
      #pragma unroll
      for (int r = 0; r < 4; ++r){
        int m = mrow + r;
        float v = acc[i][r] + bv;
        if (wmode == 0) Y[(size_t)m * N + n] = v;
        else            Y[((size_t)(m & (T_-1)) * N + n) * B_ + (m >> 9)] = v;
      }
    }
  }
}

// ---------------- fused 5-layer wavefront GRU ----------------
// 160 blocks = 5 layers x 32 subs. Round s: layer l does t = s-l.
// xp:  [T][3H][B] fp32 (layer-0 input proj, precomputed GEMM)
// wsw: swizzled bf16 W frags per block (see prep_wfrag)
// hT:  [5][2][32][512] bf16 self-recurrence double buffer (sc1 only)
// xT:  [4][4][32][512] bf16 inter-layer ring (slot t&3) (sc1 only)
// xout:[32][512][512] bf16 layer-4 output (normal stores, for FC GEMM)
__global__ __launch_bounds__(256, 1) void gru_fused(
    const float* __restrict__ xp, const unsigned short* __restrict__ wsw,
    const float* __restrict__ bias_sw, unsigned short* __restrict__ hT,
    unsigned short* __restrict__ xT, unsigned short* __restrict__ xout,
    int* __restrict__ flags){
  __shared__ unsigned short w_s[96 * 512];     // 96 KB: A-frags (g*32+ks)
  __shared__ unsigned short stage_s[32 * 512]; // 32 KB: B-frags (n*16+ks), reused h then x
  __shared__ float p_s[4][2][16][16];          // [r,z,hn,xn][ntile][unit][batch]
  __shared__ float bias_s[64];

  const int tid = threadIdx.x;
  const int blk = blockIdx.x;
  const int l   = blk >> 5;
  const int sub = blk & 31;
  const int lane = tid & 63, wave = tid >> 6;
  const int l15 = lane & 15, l4 = lane >> 4;
  const int myn = wave >> 1;            // n-tile (batch 16-group)
  const bool rzw = (wave & 1) == 0;     // waves 0,2: r+z ; waves 1,3: n-gate

  // load swizzled W + bias into LDS
  {
    const u32x4* src = (const u32x4*)(wsw + (size_t)blk * WSZ_);
    u32x4* dst = (u32x4*)w_s;
    #pragma unroll
    for (int i = 0; i < 24; ++i) dst[tid + 256 * i] = src[tid + 256 * i];
  }
  if (tid < 64) bias_s[tid] = bias_sw[blk * 64 + tid];

  // combine-thread fixed (j,b) ownership: units cj,cj+1 of this block, batch cb
  const int cb = tid & 31;
  const int cj = (tid >> 5) * 2;
  const int jg = sub * 16 + cj;
  float hres0 = 0.f, hres1 = 0.f;

  unsigned short* hTl = hT + (size_t)l * (2 * 32 * 512);
  unsigned short* xTw = xT + (size_t)l * (4 * 32 * 512);        // valid for l<4
  const unsigned short* xTr = xT + (size_t)(l - 1) * (4 * 32 * 512); // valid for l>0

  auto stage = [&](const unsigned short* __restrict__ src){
    u64 lo[8], hi[8];
    #pragma unroll
    for (int i = 0; i < 8; ++i){
      int c = tid + 256 * i;
      int f = c >> 6, lam = c & 63;
      int b = ((f >> 4) << 4) | (lam & 15);
      int k = ((f & 15) << 5) | ((lam >> 4) << 3);
      const u64* sp = (const u64*)(src + b * 512 + k);
      lo[i] = ld_coh_u64(sp);
      hi[i] = ld_coh_u64(sp + 1);
    }
    #pragma unroll
    for (int i = 0; i < 8; ++i){
      int c = tid + 256 * i;
      *(u64*)&stage_s[c * 8]     = lo[i];
      *(u64*)&stage_s[c * 8 + 4] = hi[i];
    }
  };

  __syncthreads();   // W/bias ready

  for (int s = 0; s < T_ + 4; ++s){
    const int t = s - l;
    const bool act = (t >= 0) && (t < T_);
    if (act){
      f32x4 accA = {0.f,0.f,0.f,0.f}, accB = {0.f,0.f,0.f,0.f};
      // ---- stage h(t) ----
      stage(hTl + (size_t)(t & 1) * (32 * 512));
      __syncthreads();
      // ---- MFMA over h (ksteps 0..15) ----
      #pragma unroll
      for (int ks = 0; ks < 16; ++ks){
        bf16x8 b = *(const bf16x8*)&stage_s[((myn << 4) + ks) * 512 + lane * 8];
        if (rzw){
          bf16x8 a0 = *(const bf16x8*)&w_s[(0 * 32 + ks) * 512 + lane * 8];
          bf16x8 a1 = *(const bf16x8*)&w_s[(1 * 32 + ks) * 512 + lane * 8];
          accA = __builtin_amdgcn_mfma_f32_16x16x32_bf16(a0, b, accA, 0, 0, 0);
          accB = __builtin_amdgcn_mfma_f32_16x16x32_bf16(a1, b, accB, 0, 0, 0);
        } else {
          bf16x8 a2 = *(const bf16x8*)&w_s[(2 * 32 + ks) * 512 + lane * 8];
          accA = __builtin_amdgcn_mfma_f32_16x16x32_bf16(a2, b, accA, 0, 0, 0);
        }
      }
      float er = 0.f, ez = 0.f, en = 0.f, er1 = 0.f, ez1 = 0.f, en1 = 0.f;
      if (l > 0){
        __syncthreads();          // stage buf free
        // ---- stage x = y_{l-1}(t) ----
        stage(xTr + (size_t)(t & 3) * (32 * 512));
        __syncthreads();
        // ---- MFMA over x (ksteps 16..31) ----
        #pragma unroll
        for (int ks = 0; ks < 16; ++ks){
          bf16x8 b = *(const bf16x8*)&stage_s[((myn << 4) + ks) * 512 + lane * 8];
          if (rzw){
            bf16x8 a0 = *(const bf16x8*)&w_s[(0 * 32 + 16 + ks) * 512 + lane * 8];
            bf16x8 a1 = *(const bf16x8*)&w_s[(1 * 32 + 16 + ks) * 512 + lane * 8];
            accA = __builtin_amdgcn_mfma_f32_16x16x32_bf16(a0, b, accA, 0, 0, 0);
            accB = __builtin_amdgcn_mfma_f32_16x16x32_bf16(a1, b, accB, 0, 0, 0);
          } else {
            bf16x8 a2 = *(const bf16x8*)&w_s[(2 * 32 + 16 + ks) * 512 + lane * 8];
            accB = __builtin_amdgcn_mfma_f32_16x16x32_bf16(a2, b, accB, 0, 0, 0);  // xn
          }
        }
      } else {
        // layer 0: x-projection precomputed in xp (includes bih)
        const float* xb = xp + (size_t)t * (G3H_ * B_) + cb;
        er  = xb[(size_t)(0 * H_ + jg) * B_];  er1 = xb[(size_t)(0 * H_ + jg + 1) * B_];
        ez  = xb[(size_t)(1 * H_ + jg) * B_];  ez1 = xb[(size_t)(1 * H_ + jg + 1) * B_];
        en  = xb[(size_t)(2 * H_ + jg) * B_];  en1 = xb[(size_t)(2 * H_ + jg + 1) * B_];
      }
      // ---- accs -> p_s ----
      #pragma unroll
      for (int r = 0; r < 4; ++r){
        int u = l4 * 4 + r;
        if (rzw){ p_s[0][myn][u][l15] = accA[r]; p_s[1][myn][u][l15] = accB[r]; }
        else    { p_s[2][myn][u][l15] = accA[r]; p_s[3][myn][u][l15] = accB[r]; }
      }
      __syncthreads();
      // ---- combine: gates + state update ----
      {
        const int nt = cb >> 4, bc = cb & 15;
        const float* bs = bias_s + cj * 4;
        float rp0 = p_s[0][nt][cj][bc],     rp1 = p_s[0][nt][cj + 1][bc];
        float zp0 = p_s[1][nt][cj][bc],     zp1 = p_s[1][nt][cj + 1][bc];
        float hp0 = p_s[2][nt][cj][bc],     hp1 = p_s[2][nt][cj + 1][bc];
        float xq0 = p_s[3][nt][cj][bc],     xq1 = p_s[3][nt][cj + 1][bc];
        float r0 = 1.f / (1.f + __expf(-(rp0 + er  + bs[0])));
        float r1 = 1.f / (1.f + __expf(-(rp1 + er1 + bs[4])));
        float z0 = 1.f / (1.f + __expf(-(zp0 + ez  + bs[1])));
        float z1 = 1.f / (1.f + __expf(-(zp1 + ez1 + bs[5])));
        float nx0 = (l > 0) ? (xq0 + bs[2]) : en;
        float nx1 = (l > 0) ? (xq1 + bs[6]) : en1;
        float e0 = __expf(2.f * (nx0 + r0 * (hp0 + bs[3])));
        float e1 = __expf(2.f * (nx1 + r1 * (hp1 + bs[7])));
        float n0 = (e0 - 1.f) / (e0 + 1.f);
        float n1 = (e1 - 1.f) / (e1 + 1.f);
        float h0 = (1.f - z0) * n0 + z0 * hres0; hres0 = h0;
        float h1 = (1.f - z1) * n1 + z1 * hres1; hres1 = h1;
        unsigned int pk = (unsigned int)f2bf(h0) | ((unsigned int)f2bf(h1) << 16);
        st_coh_u32(hTl + (size_t)((t + 1) & 1) * (32 * 512) + cb * 512 + jg, pk);
        if (l < 4) st_coh_u32(xTw + (size_t)(t & 3) * (32 * 512) + cb * 512 + jg, pk);
        else *(unsigned int*)&xout[((size_t)cb * T_ + t) * H_ + jg] = pk;
      }
    }
    // ---- global round barrier (fence-free, sc1 flags) ----
    __syncthreads();              // drains vmcnt: all sc1 stores at L3
    if (tid == 0) st_flag(&flags[blk], s + 1);
    if (tid < 64){
      const int tgt = s + 1;
      while (true){
        int v0 = ld_flag(&flags[tid]);
        int v1 = ld_flag(&flags[tid + 64]);
        int v2 = (tid < 32) ? ld_flag(&flags[tid + 128]) : tgt;
        if (__all(v0 >= tgt && v1 >= tgt && v2 >= tgt)) break;
      }
    }
    __syncthreads();
  }
}

extern "C" void kernel_launch(void* const* d_in, const int* in_sizes, int n_in,
                              void* d_out, int out_size, void* d_ws, size_t ws_size,
                              hipStream_t stream){
  (void)in_sizes; (void)n_in; (void)out_size; (void)ws_size;
  const int*   note  = (const int*)d_in[0];
  const int*   chord = (const int*)d_in[1];
  const float* ctab  = (const float*)d_in[2];
  const float* ntab  = (const float*)d_in[3];
  const float* wih0  = (const float*)d_in[4];
  const float* whh0  = (const float*)d_in[5];
  const float* bih0  = (const float*)d_in[6];
  const float* bhh0  = (const float*)d_in[7];
  const float* wihr  = (const float*)d_in[8];
  const float* whhr  = (const float*)d_in[9];
  const float* bihr  = (const float*)d_in[10];
  const float* bhhr  = (const float*)d_in[11];
  const float* fcw   = (const float*)d_in[12];
  const float* fcb   = (const float*)d_in[13];
  float* out = (float*)d_out;

  char* ws = (char*)d_ws;
  size_t off = 0;
  auto alloc = [&](size_t bytes)->char*{
    char* p = ws + off; off = (off + bytes + 255) & ~(size_t)255; return p;
  };
  int*            flags   = (int*)alloc((size_t)NBF_ * sizeof(int));
  float*          xp      = (float*)alloc((size_t)BT_ * G3H_ * 4);
  unsigned short* x0      = (unsigned short*)alloc((size_t)BT_ * K0_ * 2);
  unsigned short* xout    = (unsigned short*)alloc((size_t)BT_ * H_ * 2);
  unsigned short* hT      = (unsigned short*)alloc((size_t)5 * 2 * 32 * 512 * 2);
  unsigned short* xT      = (unsigned short*)alloc((size_t)4 * 4 * 32 * 512 * 2);
  unsigned short* wsw     = (unsigned short*)alloc((size_t)NBF_ * WSZ_ * 2);
  float*          bias_sw = (float*)alloc((size_t)NBF_ * 64 * 4);
  unsigned short* wih0_b  = (unsigned short*)alloc((size_t)G3H_ * K0_ * 2);
  unsigned short* fcw_b   = (unsigned short*)alloc((size_t)CV_ * H_ * 2);

  hipMemsetAsync(flags, 0, (size_t)NBF_ * sizeof(int), stream);
  hipMemsetAsync(hT, 0, (size_t)5 * 2 * 32 * 512 * 2, stream);

  { int n = G3H_ * K0_; convert_bf16<<<(n + 255) / 256, 256, 0, stream>>>(wih0, wih0_b, n); }
  { int n = CV_ * H_;   convert_bf16<<<(n + 255) / 256, 256, 0, stream>>>(fcw, fcw_b, n); }
  { int n = NBF_ * WSZ_;
    prep_wfrag<<<(n + 255) / 256, 256, 0, stream>>>(whh0, whhr, wihr, wsw, n); }
  { int n = NBF_ * 64;
    prep_bias<<<(n + 255) / 256, 256, 0, stream>>>(bhh0, bihr, bhhr, bias_sw, n); }

  emb_kernel<<<BT_, 64, 0, stream>>>(note, chord, ctab, ntab, x0);

  // layer-0 input projection: xp = x0 @ wih0^T + bih0, layout [T][3H][B]
  gemm_bt<<<dim3(G3H_ / 64, BT_ / 64), 256, 0, stream>>>(x0, wih0_b, bih0, xp, BT_, G3H_, K0_, 1);

  // fused 5-layer wavefront recurrence
  gru_fused<<<NBF_, 256, 0, stream>>>(xp, wsw, bias_sw, hT, xT, xout, flags);

  // FC: out = xout @ fcw^T + fcb
  gemm_bt<<<dim3((CV_ + 63) / 64, BT_ / 64), 256, 0, stream>>>(
      xout, fcw_b, fcb, out, BT_, CV_, H_, 0);
}

// Round 5
// 6090.332 us; speedup vs baseline: 17.3121x; 1.0479x over previous
//
#include <hip/hip_runtime.h>
#include <hip/hip_bf16.h>

#define B_   32
#define T_   512
#define NN_  16
#define CV_  150
#define D_   512
#define H_   512
#define BT_  16384      // B*T
#define K0_  1024       // 2*D
#define G3H_ 1536       // 3*H
#define SUBS_ 32        // blocks per layer in fused kernel
#define NBF_ 160        // 5 * SUBS_
#define WSZ_ 49152      // bf16 elems of swizzled W per block (96 frags * 512)

using bf16x8 = __attribute__((ext_vector_type(8))) short;
using f32x4  = __attribute__((ext_vector_type(4))) float;
using u32x4  = __attribute__((ext_vector_type(4))) unsigned int;
typedef unsigned long long u64;

__device__ __forceinline__ unsigned short f2bf(float f){
  unsigned int u = __builtin_bit_cast(unsigned int, f);
  u += 0x7fffu + ((u >> 16) & 1u);           // RNE
  return (unsigned short)(u >> 16);
}

__device__ __forceinline__ void store8(unsigned short* p, f32x4 a, f32x4 b){
  union { unsigned short us[8]; u32x4 v; } u;
  u.us[0]=f2bf(a[0]); u.us[1]=f2bf(a[1]); u.us[2]=f2bf(a[2]); u.us[3]=f2bf(a[3]);
  u.us[4]=f2bf(b[0]); u.us[5]=f2bf(b[1]); u.us[6]=f2bf(b[2]); u.us[7]=f2bf(b[3]);
  *(u32x4*)p = u.v;
}

// coherent (L3-level) helpers: relaxed agent-scope atomics -> sc1 ops, NO fences
__device__ __forceinline__ u64 ld_coh_u64(const u64* p){
  return __hip_atomic_load(p, __ATOMIC_RELAXED, __HIP_MEMORY_SCOPE_AGENT);
}
__device__ __forceinline__ void st_coh_u32(void* p, unsigned int v){
  __hip_atomic_store((unsigned int*)p, v, __ATOMIC_RELAXED, __HIP_MEMORY_SCOPE_AGENT);
}
__device__ __forceinline__ void st_flag(int* p, int v){
  __hip_atomic_store(p, v, __ATOMIC_RELAXED, __HIP_MEMORY_SCOPE_AGENT);
}
__device__ __forceinline__ int ld_flag(const int* p){
  return __hip_atomic_load(p, __ATOMIC_RELAXED, __HIP_MEMORY_SCOPE_AGENT);
}

// ---------------- fp32 -> bf16 weight conversion ----------------
__global__ void convert_bf16(const float* __restrict__ src,
                             unsigned short* __restrict__ dst, int n){
  int i = blockIdx.x * 256 + threadIdx.x;
  if (i < n) dst[i] = f2bf(src[i]);
}

// ---------------- swizzle W into MFMA A-frag layout ----------------
// wsw[blk=l*32+sub][fragl=g*32+ks][lam*8+e] ; ks<16 = Whh kstep, ks>=16 = Wih kstep
// row = g*512 + sub*16 + (lam&15); k = (ks&15)*32 + (lam>>4)*8 + e
__global__ void prep_wfrag(const float* __restrict__ whh0,
                           const float* __restrict__ whhr,
                           const float* __restrict__ wihr,
                           unsigned short* __restrict__ wsw, int total){
  int idx = blockIdx.x * 256 + threadIdx.x;
  if (idx >= total) return;
  int pos = idx & 511;
  int lam = pos >> 3, e = pos & 7;
  int fr  = idx >> 9;
  int ks  = fr & 31;
  int g   = (fr >> 5) % 3;
  int blk = fr / 96;
  int sub = blk & 31, l = blk >> 5;
  int row = g * 512 + sub * 16 + (lam & 15);
  int k   = (ks & 15) * 32 + (lam >> 4) * 8 + e;
  float v;
  if (l == 0) v = (ks < 16) ? whh0[(size_t)row * H_ + k] : 0.f;
  else {
    const float* w = (ks < 16) ? (whhr + (size_t)(l - 1) * G3H_ * H_)
                               : (wihr + (size_t)(l - 1) * G3H_ * H_);
    v = w[(size_t)row * H_ + k];
  }
  wsw[idx] = f2bf(v);
}

// bias_sw[blk][u][q]: q=0 r-bias, 1 z-bias, 2 xn-bias(bih_n), 3 hn-bias(bhh_n)
// l==0: xp already contains bih -> r/z use bhh only, q2 = 0
__global__ void prep_bias(const float* __restrict__ bhh0,
                          const float* __restrict__ bihr,
                          const float* __restrict__ bhhr,
                          float* __restrict__ bias_sw, int total){
  int idx = blockIdx.x * 256 + threadIdx.x;
  if (idx >= total) return;
  int q = idx & 3, u = (idx >> 2) & 15, sub = (idx >> 6) & 31, l = idx >> 11;
  int j = sub * 16 + u;
  float v;
  if (l == 0){
    v = (q == 0) ? bhh0[j] : (q == 1) ? bhh0[512 + j] : (q == 2) ? 0.f : bhh0[1024 + j];
  } else {
    const float* bi = bihr + (size_t)(l - 1) * G3H_;
    const float* bh = bhhr + (size_t)(l - 1) * G3H_;
    v = (q == 0) ? bi[j] + bh[j]
      : (q == 1) ? bi[512 + j] + bh[512 + j]
      : (q == 2) ? bi[1024 + j] : bh[1024 + j];
  }
  bias_sw[idx] = v;
}

// ---------------- embeddings ----------------
__global__ __launch_bounds__(64) void emb_kernel(
    const int* __restrict__ note, const int* __restrict__ chord,
    const float* __restrict__ ctab, const float* __restrict__ ntab,
    unsigned short* __restrict__ x0){
  const int bt = blockIdx.x;
  const int tid = threadIdx.x;
  __shared__ int sn[NN_];
  if (tid < NN_) sn[tid] = note[bt * NN_ + tid];
  __syncthreads();
  float alive = 1.f, cnt = 0.f;
  float msk[NN_];
  #pragma unroll
  for (int k = 0; k < NN_; ++k){ if (sn[k] == 0) alive = 0.f; msk[k] = alive; cnt += alive; }
  const float inv = 1.f / fmaxf(cnt, 1.f);
  const int ch = chord[bt];
  const int d0 = tid * 8;
  f32x4 c0 = {0.f,0.f,0.f,0.f}, c1 = {0.f,0.f,0.f,0.f};
  if (ch != 0){
    const float* cp = ctab + (size_t)ch * D_ + d0;
    c0 = *(const f32x4*)cp; c1 = *(const f32x4*)(cp + 4);
  }
  f32x4 s0 = {0.f,0.f,0.f,0.f}, s1 = {0.f,0.f,0.f,0.f};
  #pragma unroll
  for (int k = 0; k < NN_; ++k){
    if (msk[k] != 0.f){
      const float* np = ntab + (size_t)sn[k] * D_ + d0;
      s0 += *(const f32x4*)np;
      s1 += *(const f32x4*)(np + 4);
    }
  }
  s0 *= inv; s1 *= inv;
  unsigned short* o = x0 + (size_t)bt * K0_ + d0;
  store8(o, c0, c1);
  store8(o + D_, s0, s1);
}

// ---------------- bf16 MFMA GEMM:  Y = X[M,K] @ W[N,K]^T + bias ----------------
__global__ __launch_bounds__(256) void gemm_bt(
    const unsigned short* __restrict__ X, const unsigned short* __restrict__ W,
    const float* __restrict__ bias, float* __restrict__ Y,
    int M, int N, int K, int wmode){
  const int lane = threadIdx.x & 63;
  const int wave = threadIdx.x >> 6;
  const int l15 = lane & 15, kq4 = lane >> 4;
  const int m_frag = blockIdx.y * 64 + wave * 16 + l15;
  const int n_base = blockIdx.x * 64;
  f32x4 acc[4] = {{0.f,0.f,0.f,0.f},{0.f,0.f,0.f,0.f},{0.f,0.f,0.f,0.f},{0.f,0.f,0.f,0.f}};
  const unsigned short* xptr = X + (size_t)m_frag * K + kq4 * 8;
  const unsigned short* wptr[4];
  #pragma unroll
  for (int i = 0; i < 4; ++i){
    int n = n_base + i * 16 + l15;
    if (n >= N) n = N - 1;
    wptr[i] = W + (size_t)n * K + kq4 * 8;
  }
  for (int k0 = 0; k0 < K; k0 += 32){
    bf16x8 a = *(const bf16x8*)(xptr + k0);
    #pragma unroll
    for (int i = 0; i < 4; ++i){
      bf16x8 b = *(const bf16x8*)(wptr[i] + k0);
      acc[i] = __builtin_amdgcn_mfma_f32_16x16x32_bf16(a, b, acc[i], 0, 0, 0);
    }
  }
  const int mrow = blockIdx.y * 64 + wave * 16 + kq4 * 4;
  #pragma unroll
  for (int i = 0; i < 4; ++i){
    int n = n_base + i * 16 + l15;
    if (n < N){
      float bv = bias[n];
      #pragma unroll
      for (int r = 0; r < 4; ++r){
        int m = mrow + r;
        float v = acc[i][r] + bv;
        if (wmode == 0) Y[(size_t)m * N + n] = v;
        else            Y[((size_t)(m & (T_-1)) * N + n) * B_ + (m >> 9)] = v;
      }
    }
  }
}

// ---------------- fused 5-layer pipelined GRU, NO global barrier ----------------
// 160 blocks = 5 layers x 32 subs. Each layer runs its own t=0..511, gated by
// per-layer done-counters: flags[l*64+sub] = number of completed steps.
// Gate for (l, step t): own >= t ; producer >= t+1 ; consumer >= t-3 (ring depth 4).
// hT:  [5][2][32][512] bf16 self-recurrence double buffer (sc1 only)
// xT:  [4][4][32][512] bf16 inter-layer ring (slot t&3) (sc1 only)
__global__ __launch_bounds__(256, 1) void gru_fused(
    const float* __restrict__ xp, const unsigned short* __restrict__ wsw,
    const float* __restrict__ bias_sw, unsigned short* __restrict__ hT,
    unsigned short* __restrict__ xT, unsigned short* __restrict__ xout,
    int* __restrict__ flags){
  __shared__ unsigned short w_s[96 * 512];     // 96 KB: A-frags (g*32+ks)
  __shared__ unsigned short stage_s[32 * 512]; // 32 KB: h B-frags
  __shared__ float p_s[4][2][16][16];          // [r,z,hn,xn][ntile][unit][batch]

  const int tid = threadIdx.x;
  const int blk = blockIdx.x;
  const int l   = blk >> 5;
  const int sub = blk & 31;
  const int lane = tid & 63, wave = tid >> 6;
  const int l15 = lane & 15, l4 = lane >> 4;
  const int myn = wave >> 1;            // n-tile (batch 16-group)
  const bool rzw = (wave & 1) == 0;     // waves 0,2: r+z ; waves 1,3: n-gate

  // load swizzled W into LDS
  {
    const u32x4* src = (const u32x4*)(wsw + (size_t)blk * WSZ_);
    u32x4* dst = (u32x4*)w_s;
    #pragma unroll
    for (int i = 0; i < 24; ++i) dst[tid + 256 * i] = src[tid + 256 * i];
  }

  // combine-thread fixed (j,b) ownership + biases in registers
  const int cb = tid & 31;
  const int cj = (tid >> 5) * 2;
  const int jg = sub * 16 + cj;
  const float* bsp = bias_sw + blk * 64;
  const float br0 = bsp[cj*4+0],     bz0 = bsp[cj*4+1],     bx0 = bsp[cj*4+2],     bn0 = bsp[cj*4+3];
  const float br1 = bsp[(cj+1)*4+0], bz1 = bsp[(cj+1)*4+1], bx1 = bsp[(cj+1)*4+2], bn1 = bsp[(cj+1)*4+3];
  float hres0 = 0.f, hres1 = 0.f;

  unsigned short* hTl = hT + (size_t)l * (2 * 32 * 512);
  unsigned short* xTw = xT + (size_t)l * (4 * 32 * 512);             // l<4
  const unsigned short* xTr = xT + (size_t)(l - 1) * (4 * 32 * 512); // l>0
  int*       fl_own  = flags + l * 64;
  const int* fl_prod = flags + (l > 0 ? (l - 1) * 64 : l * 64);
  const int* fl_cons = flags + (l + 1) * 64;                         // l<4

  __syncthreads();   // W ready

  for (int t = 0; t < T_; ++t){
    // ---- gate: own h-barrier + producer-ahead + consumer back-pressure ----
    if (wave == 0){
      const int* pp; int tgt;
      if (lane < 32){ pp = fl_own + lane; tgt = t; }
      else if (l > 0){ pp = fl_prod + (lane - 32); tgt = t + 1; }
      else { pp = fl_own + (lane - 32); tgt = -(1 << 30); }
      while (true){ int v = ld_flag(pp); if (__all(v >= tgt)) break; }
    } else if (wave == 1 && l < 4){
      const int* pp = fl_cons + (lane & 31);
      const int tgt = t - 3;
      while (true){
        int v = (lane < 32) ? ld_flag(pp) : 0x7fffffff;
        if (__all(v >= tgt)) break;
      }
    }
    __syncthreads();

    // ---- layer-0 x-projection prefetch (cached; independent of gates) ----
    float er = 0.f, ez = 0.f, en = 0.f, er1 = 0.f, ez1 = 0.f, en1 = 0.f;
    if (l == 0){
      const float* xb = xp + (size_t)t * (G3H_ * B_) + cb;
      er  = xb[(size_t)(0 * H_ + jg) * B_];  er1 = xb[(size_t)(0 * H_ + jg + 1) * B_];
      ez  = xb[(size_t)(1 * H_ + jg) * B_];  ez1 = xb[(size_t)(1 * H_ + jg + 1) * B_];
      en  = xb[(size_t)(2 * H_ + jg) * B_];  en1 = xb[(size_t)(2 * H_ + jg + 1) * B_];
    }

    // ---- stage h(t) -> LDS (single phase) ----
    {
      const unsigned short* hsrc = hTl + (size_t)(t & 1) * (32 * 512);
      u64 lo[8], hi[8];
      #pragma unroll
      for (int i = 0; i < 8; ++i){
        int c = tid + 256 * i;               // c in [0,2048)
        int f = c >> 6, lam = c & 63;
        int b = ((f >> 4) << 4) | (lam & 15);
        int k = ((f & 15) << 5) | ((lam >> 4) << 3);
        const u64* sp = (const u64*)(hsrc + b * 512 + k);
        lo[i] = ld_coh_u64(sp);
        hi[i] = ld_coh_u64(sp + 1);
      }
      #pragma unroll
      for (int i = 0; i < 8; ++i){
        int c = tid + 256 * i;
        *(u64*)&stage_s[c * 8]     = lo[i];
        *(u64*)&stage_s[c * 8 + 4] = hi[i];
      }
    }

    // ---- x(t) B-frags: direct global(sc1) -> VGPR (latency hides under h-MFMA) ----
    union Ufrag { u64 q[2]; bf16x8 v; };
    Ufrag xb[16];
    if (l > 0){
      const unsigned short* xs = xTr + (size_t)(t & 3) * (32 * 512)
                               + (size_t)(myn * 16 + l15) * 512 + l4 * 8;
      #pragma unroll
      for (int ks = 0; ks < 16; ++ks){
        const u64* sp = (const u64*)(xs + ks * 32);
        xb[ks].q[0] = ld_coh_u64(sp);
        xb[ks].q[1] = ld_coh_u64(sp + 1);
      }
    }
    __syncthreads();   // h stage ready

    // ---- MFMA: h part (ks 0..15, B from LDS) ----
    f32x4 accA = {0.f,0.f,0.f,0.f}, accB = {0.f,0.f,0.f,0.f};
    #pragma unroll
    for (int ks = 0; ks < 16; ++ks){
      bf16x8 b = *(const bf16x8*)&stage_s[((myn << 4) + ks) * 512 + lane * 8];
      if (rzw){
        bf16x8 a0 = *(const bf16x8*)&w_s[(0 * 32 + ks) * 512 + lane * 8];
        bf16x8 a1 = *(const bf16x8*)&w_s[(1 * 32 + ks) * 512 + lane * 8];
        accA = __builtin_amdgcn_mfma_f32_16x16x32_bf16(a0, b, accA, 0, 0, 0);
        accB = __builtin_amdgcn_mfma_f32_16x16x32_bf16(a1, b, accB, 0, 0, 0);
      } else {
        bf16x8 a2 = *(const bf16x8*)&w_s[(2 * 32 + ks) * 512 + lane * 8];
        accA = __builtin_amdgcn_mfma_f32_16x16x32_bf16(a2, b, accA, 0, 0, 0);
      }
    }
    // ---- MFMA: x part (ks 16..31, B from regs) ----
    if (l > 0){
      #pragma unroll
      for (int ks = 0; ks < 16; ++ks){
        bf16x8 b = xb[ks].v;
        if (rzw){
          bf16x8 a0 = *(const bf16x8*)&w_s[(0 * 32 + 16 + ks) * 512 + lane * 8];
          bf16x8 a1 = *(const bf16x8*)&w_s[(1 * 32 + 16 + ks) * 512 + lane * 8];
          accA = __builtin_amdgcn_mfma_f32_16x16x32_bf16(a0, b, accA, 0, 0, 0);
          accB = __builtin_amdgcn_mfma_f32_16x16x32_bf16(a1, b, accB, 0, 0, 0);
        } else {
          bf16x8 a2 = *(const bf16x8*)&w_s[(2 * 32 + 16 + ks) * 512 + lane * 8];
          accB = __builtin_amdgcn_mfma_f32_16x16x32_bf16(a2, b, accB, 0, 0, 0);  // xn
        }
      }
    }
    // ---- accs -> p_s ----
    #pragma unroll
    for (int r = 0; r < 4; ++r){
      int u = l4 * 4 + r;
      if (rzw){ p_s[0][myn][u][l15] = accA[r]; p_s[1][myn][u][l15] = accB[r]; }
      else    { p_s[2][myn][u][l15] = accA[r]; p_s[3][myn][u][l15] = accB[r]; }
    }
    __syncthreads();

    // ---- combine: gates + state update ----
    {
      const int nt = cb >> 4, bc = cb & 15;
      float rp0 = p_s[0][nt][cj][bc],     rp1 = p_s[0][nt][cj + 1][bc];
      float zp0 = p_s[1][nt][cj][bc],     zp1 = p_s[1][nt][cj + 1][bc];
      float hp0 = p_s[2][nt][cj][bc],     hp1 = p_s[2][nt][cj + 1][bc];
      float xq0 = p_s[3][nt][cj][bc],     xq1 = p_s[3][nt][cj + 1][bc];
      float r0 = 1.f / (1.f + __expf(-(rp0 + er  + br0)));
      float r1 = 1.f / (1.f + __expf(-(rp1 + er1 + br1)));
      float z0 = 1.f / (1.f + __expf(-(zp0 + ez  + bz0)));
      float z1 = 1.f / (1.f + __expf(-(zp1 + ez1 + bz1)));
      float nx0 = (l > 0) ? (xq0 + bx0) : en;
      float nx1 = (l > 0) ? (xq1 + bx1) : en1;
      float e0 = __expf(2.f * (nx0 + r0 * (hp0 + bn0)));
      float e1 = __expf(2.f * (nx1 + r1 * (hp1 + bn1)));
      float n0 = (e0 - 1.f) / (e0 + 1.f);
      float n1 = (e1 - 1.f) / (e1 + 1.f);
      float h0 = (1.f - z0) * n0 + z0 * hres0; hres0 = h0;
      float h1 = (1.f - z1) * n1 + z1 * hres1; hres1 = h1;
      unsigned int pk = (unsigned int)f2bf(h0) | ((unsigned int)f2bf(h1) << 16);
      st_coh_u32(hTl + (size_t)((t + 1) & 1) * (32 * 512) + cb * 512 + jg, pk);
      if (l < 4) st_coh_u32(xTw + (size_t)(t & 3) * (32 * 512) + cb * 512 + jg, pk);
      else *(unsigned int*)&xout[((size_t)cb * T_ + t) * H_ + jg] = pk;
    }
    __syncthreads();              // drains vmcnt: all sc1 stores at L3
    if (tid == 0) st_flag(fl_own + sub, t + 1);
  }
}

extern "C" void kernel_launch(void* const* d_in, const int* in_sizes, int n_in,
                              void* d_out, int out_size, void* d_ws, size_t ws_size,
                              hipStream_t stream){
  (void)in_sizes; (void)n_in; (void)out_size; (void)ws_size;
  const int*   note  = (const int*)d_in[0];
  const int*   chord = (const int*)d_in[1];
  const float* ctab  = (const float*)d_in[2];
  const float* ntab  = (const float*)d_in[3];
  const float* wih0  = (const float*)d_in[4];
  const float* whh0  = (const float*)d_in[5];
  const float* bih0  = (const float*)d_in[6];
  const float* bhh0  = (const float*)d_in[7];
  const float* wihr  = (const float*)d_in[8];
  const float* whhr  = (const float*)d_in[9];
  const float* bihr  = (const float*)d_in[10];
  const float* bhhr  = (const float*)d_in[11];
  const float* fcw   = (const float*)d_in[12];
  const float* fcb   = (const float*)d_in[13];
  float* out = (float*)d_out;

  char* ws = (char*)d_ws;
  size_t off = 0;
  auto alloc = [&](size_t bytes)->char*{
    char* p = ws + off; off = (off + bytes + 255) & ~(size_t)255; return p;
  };
  int*            flags   = (int*)alloc((size_t)5 * 64 * sizeof(int));
  float*          xp      = (float*)alloc((size_t)BT_ * G3H_ * 4);
  unsigned short* x0      = (unsigned short*)alloc((size_t)BT_ * K0_ * 2);
  unsigned short* xout    = (unsigned short*)alloc((size_t)BT_ * H_ * 2);
  unsigned short* hT      = (unsigned short*)alloc((size_t)5 * 2 * 32 * 512 * 2);
  unsigned short* xT      = (unsigned short*)alloc((size_t)4 * 4 * 32 * 512 * 2);
  unsigned short* wsw     = (unsigned short*)alloc((size_t)NBF_ * WSZ_ * 2);
  float*          bias_sw = (float*)alloc((size_t)NBF_ * 64 * 4);
  unsigned short* wih0_b  = (unsigned short*)alloc((size_t)G3H_ * K0_ * 2);
  unsigned short* fcw_b   = (unsigned short*)alloc((size_t)CV_ * H_ * 2);

  hipMemsetAsync(flags, 0, (size_t)5 * 64 * sizeof(int), stream);
  hipMemsetAsync(hT, 0, (size_t)5 * 2 * 32 * 512 * 2, stream);

  { int n = G3H_ * K0_; convert_bf16<<<(n + 255) / 256, 256, 0, stream>>>(wih0, wih0_b, n); }
  { int n = CV_ * H_;   convert_bf16<<<(n + 255) / 256, 256, 0, stream>>>(fcw, fcw_b, n); }
  { int n = NBF_ * WSZ_;
    prep_wfrag<<<(n + 255) / 256, 256, 0, stream>>>(whh0, whhr, wihr, wsw, n); }
  { int n = NBF_ * 64;
    prep_bias<<<(n + 255) / 256, 256, 0, stream>>>(bhh0, bihr, bhhr, bias_sw, n); }

  emb_kernel<<<BT_, 64, 0, stream>>>(note, chord, ctab, ntab, x0);

  // layer-0 input projection: xp = x0 @ wih0^T + bih0, layout [T][3H][B]
  gemm_bt<<<dim3(G3H_ / 64, BT_ / 64), 256, 0, stream>>>(x0, wih0_b, bih0, xp, BT_, G3H_, K0_, 1);

  // fused 5-layer pipelined recurrence (no global barrier)
  gru_fused<<<NBF_, 256, 0, stream>>>(xp, wsw, bias_sw, hT, xT, xout, flags);

  // FC: out = xout @ fcw^T + fcb
  gemm_bt<<<dim3((CV_ + 63) / 64, BT_ / 64), 256, 0, stream>>>(
      xout, fcw_b, fcb, out, BT_, CV_, H_, 0);
}